// Round 9
// baseline (140.695 us; speedup 1.0000x reference)
//
#include <hip/hip_runtime.h>

#define DIM 512
#define HID 2048
#define NEXP 8

typedef __attribute__((ext_vector_type(8))) short v8s;   // 8 x bf16 bits
typedef __attribute__((ext_vector_type(4))) float v4f;   // MFMA accumulator

__device__ __forceinline__ unsigned short f2bf(float f) {
  union { __bf16 b; unsigned short u; } c;
  c.b = (__bf16)f;
  return c.u;
}

__device__ __forceinline__ void gload16(const void* g, void* l) {
  __builtin_amdgcn_global_load_lds(
      (const __attribute__((address_space(1))) unsigned int*)g,
      (__attribute__((address_space(3))) unsigned int*)l, 16, 0, 0);
}

// ---------------- routing prep ----------------
__global__ void route_prep(const int* __restrict__ route, int* __restrict__ meta, int ntok) {
  __shared__ int c[NEXP];
  int t = threadIdx.x;
  if (t < NEXP) c[t] = 0;
  __syncthreads();
  for (int n = t; n < ntok; n += blockDim.x) atomicAdd(&c[route[n]], 1);
  __syncthreads();
  if (t == 0) {
    int acc = 0, pacc = 0;
    for (int e = 0; e < NEXP; ++e) {
      meta[e] = c[e];            // count
      meta[NEXP + e] = acc;      // exact offset
      meta[2 * NEXP + e] = acc;  // cursor for fill_perm
      meta[3 * NEXP + e] = pacc; // 128-padded offset (panel rows)
      acc += c[e];
      pacc += ((c[e] + 127) >> 7) << 7;
    }
  }
}

__global__ void fill_perm(const int* __restrict__ route, int* __restrict__ meta,
                          int* __restrict__ perm, int ntok) {
  int n = blockIdx.x * blockDim.x + threadIdx.x;
  if (n < ntok) {
    int p = atomicAdd(&meta[2 * NEXP + route[n]], 1);
    perm[p] = n;
  }
}

// ---------------- x conversion: gathered bf16 A-panels ----------------
// xp per 64-row tile: [kq 0..63][row 0..63][8k] bf16 = 32768 ushorts (64 KB).
// Writes ALL 128-padded tiles (dup-clamped rows) so GEMM reads are deterministic.
__global__ __launch_bounds__(256) void x_conv(
    const float* __restrict__ x, const int* __restrict__ meta,
    const int* __restrict__ perm, unsigned short* __restrict__ xp)
{
  const int bid = blockIdx.x;
  const int e = bid & 7;
  const int mt = bid >> 3;
  const int cnt = meta[e];
  const int padded = ((cnt + 127) >> 7) << 7;
  if (mt * 64 >= padded) return;
  const int off  = meta[NEXP + e];
  const int poff = meta[3 * NEXP + e];
  const int t = threadIdx.x;
  const int r = t & 63, q = t >> 6;          // row, quarter (128 floats)
  int arow = mt * 64 + r; if (arow >= cnt) arow = cnt - 1;  // clamp (dup rows)
  const float* src = x + (size_t)perm[off + arow] * DIM + q * 128;
  unsigned short* dst = xp + (size_t)((poff + mt * 64) >> 6) * 32768;
  #pragma unroll
  for (int j = 0; j < 16; ++j) {
    float4 f0 = ((const float4*)src)[2 * j];
    float4 f1 = ((const float4*)src)[2 * j + 1];
    v8s v;
    v[0] = (short)f2bf(f0.x); v[1] = (short)f2bf(f0.y);
    v[2] = (short)f2bf(f0.z); v[3] = (short)f2bf(f0.w);
    v[4] = (short)f2bf(f1.x); v[5] = (short)f2bf(f1.y);
    v[6] = (short)f2bf(f1.z); v[7] = (short)f2bf(f1.w);
    *(v8s*)(dst + (size_t)((q * 16 + j) * 64 + r) * 8) = v;
  }
}

// ---------------- GEMM1: h = silu(x@wg+bg)*(x@wi+bi) -> hbuf panels ----------------
// BM=128, BN=64(G)+64(I), BK=32, 256 thr, 4 waves (wm x wn), wave 64m x 32n x both.
// A via 2x gload16 from xp panels; weights via 4x dwordx4 (n-contig) + in-reg
// 4x4 transpose + 4x ds_write_b64 into [oct][n][8k] panel. Counted-vmcnt pipeline.
__global__ __launch_bounds__(256, 3) void gemm1n(
    const unsigned short* __restrict__ xp,
    const float* __restrict__ wg_, const float* __restrict__ bg_,
    const float* __restrict__ wi_, const float* __restrict__ bi_,
    const int* __restrict__ meta,
    unsigned short* __restrict__ hbuf)
{
  const int bid = blockIdx.x;
  const int stripe = bid & 255;        // e*32+j: same stripe -> same XCD (256%8==0)
  const int mt = bid >> 8;
  const int e = stripe >> 5, j = stripe & 31;
  const int cnt = meta[e];
  const int m0 = mt * 128;
  if (m0 >= cnt) return;
  const int poff = meta[3 * NEXP + e];
  const int n0 = j * 64;

  // per buf (16384 B): A[4 kq][128 m][8] @0 (8K) | G[4 oct][64 n][8] @8192 (4K) | I @12288 (4K)
  __shared__ __align__(16) unsigned char lds[32768];

  const int t = threadIdx.x;
  const int l = t & 63, w = t >> 6;
  const int wm = w >> 1, wn = w & 1;
  const int fr = l & 15, fg = l >> 4;

  const int tile0 = (poff + m0) >> 6;  // A spans xp tiles tile0, tile0+1

  // W staging map: ko = t&7 (k = ko*4+q), nq = t>>3 (0..31: <16 -> G, else I)
  const int ko = t & 7, nq = t >> 3;
  const int wcol = (nq & 15) * 4;
  const float* wsrc = ((nq < 16) ? wg_ : wi_) + (size_t)e * DIM * HID + n0 + wcol;
  const int wpan = 8192 + ((nq < 16) ? 0 : 4096);
  const int woct = ko >> 1, whalf = ko & 1;

  v4f aG[4][2], aI[4][2];
  #pragma unroll
  for (int i = 0; i < 4; ++i)
    #pragma unroll
    for (int q = 0; q < 2; ++q) {
      aG[i][q] = (v4f){0.f, 0.f, 0.f, 0.f};
      aI[i][q] = (v4f){0.f, 0.f, 0.f, 0.f};
    }

  float4 ld0, ld1, ld2, ld3;           // W stage regs (4 k x 4 n)
  auto wload = [&](int s) {            // 4 dwordx4, n-contiguous
    const float* b = wsrc + (size_t)(s * 32 + ko * 4) * HID;
    ld0 = *(const float4*)(b);
    ld1 = *(const float4*)(b + HID);
    ld2 = *(const float4*)(b + 2 * HID);
    ld3 = *(const float4*)(b + 3 * HID);
  };
  auto wstore = [&](int b) {           // transpose 4x4 -> 4 b64 half-slots
    unsigned char* base = lds + b * 16384 + wpan;
    const float* f0 = (const float*)&ld0;
    const float* f1 = (const float*)&ld1;
    const float* f2 = (const float*)&ld2;
    const float* f3 = (const float*)&ld3;
    #pragma unroll
    for (int i = 0; i < 4; ++i) {
      ushort4 v;
      v.x = f2bf(f0[i]); v.y = f2bf(f1[i]);
      v.z = f2bf(f2[i]); v.w = f2bf(f3[i]);
      *(ushort4*)(base + (woct * 64 + wcol + i) * 16 + whalf * 8) = v;
    }
  };
  auto aload = [&](int s, int b) {     // 2 gload16: chunks c = t + 256*i
    #pragma unroll
    for (int i = 0; i < 2; ++i) {
      const int c = t + 256 * i;
      const int kq = c >> 7, m = c & 127;
      gload16(xp + (size_t)(tile0 + (m >> 6)) * 32768 + ((size_t)(s * 4 + kq) * 64 + (m & 63)) * 8,
              lds + b * 16384 + c * 16);
    }
  };

  // prologue
  wload(0);
  wstore(0);                           // compiler waits vmcnt(0)
  aload(0, 0);
  __builtin_amdgcn_sched_barrier(0);   // REQUIRED: pin wload(1) BELOW aload(0) so
                                       // vmcnt(4) retires the gload16s, not the wloads
  wload(1);
  asm volatile("s_waitcnt vmcnt(4) lgkmcnt(0)" ::: "memory");  // retire aload(0)
  __builtin_amdgcn_sched_barrier(0);
  __builtin_amdgcn_s_barrier();
  __builtin_amdgcn_sched_barrier(0);

  int cur = 0;
  for (int s = 0; s < 16; ++s) {       // K = 512 in 32-wide steps
    if (s < 15) aload(s + 1, cur ^ 1); // issue FIRST (max in-flight window)
    const unsigned char* base = lds + cur * 16384;
    v8s af[4], gf[2], inf[2];
    #pragma unroll
    for (int mf = 0; mf < 4; ++mf)
      af[mf] = *(const v8s*)(base + (fg * 128 + wm * 64 + mf * 16 + fr) * 16);
    #pragma unroll
    for (int nf = 0; nf < 2; ++nf) {
      gf[nf]  = *(const v8s*)(base + 8192  + (fg * 64 + wn * 32 + nf * 16 + fr) * 16);
      inf[nf] = *(const v8s*)(base + 12288 + (fg * 64 + wn * 32 + nf * 16 + fr) * 16);
    }
    #pragma unroll
    for (int mf = 0; mf < 4; ++mf)
      #pragma unroll
      for (int nf = 0; nf < 2; ++nf) {
        aG[mf][nf] = __builtin_amdgcn_mfma_f32_16x16x32_bf16(af[mf], gf[nf],  aG[mf][nf], 0, 0, 0);
        aI[mf][nf] = __builtin_amdgcn_mfma_f32_16x16x32_bf16(af[mf], inf[nf], aI[mf][nf], 0, 0, 0);
      }
    if (s < 15) {
      __builtin_amdgcn_sched_barrier(0);
      wstore(cur ^ 1);                 // implicit vmcnt(2): wload(s+1) in flight a full step
      if (s < 14) {
        wload(s + 2);
        asm volatile("s_waitcnt vmcnt(4) lgkmcnt(0)" ::: "memory");  // retire aload(s+1)
      } else {
        asm volatile("s_waitcnt vmcnt(0) lgkmcnt(0)" ::: "memory");
      }
      __builtin_amdgcn_sched_barrier(0);
      __builtin_amdgcn_s_barrier();
      __builtin_amdgcn_sched_barrier(0);
    }
    cur ^= 1;
  }

  // epilogue: bias + SiLU(gate)*in -> hbuf panels (unguarded: padded rows deterministic)
  #pragma unroll
  for (int nf = 0; nf < 2; ++nf) {
    const int c = n0 + wn * 32 + nf * 16 + fr;        // k-dim of gemm2
    const float bg = bg_[(size_t)e * HID + c];
    const float bi = bi_[(size_t)e * HID + c];
    #pragma unroll
    for (int mf = 0; mf < 4; ++mf)
      #pragma unroll
      for (int jj = 0; jj < 4; ++jj) {
        const int r = wm * 64 + mf * 16 + fg * 4 + jj;  // 0..127
        const float g = aG[mf][nf][jj] + bg;
        const float v = aI[mf][nf][jj] + bi;
        const float hval = g / (1.f + __expf(-g)) * v;
        const int grow = poff + m0 + r;
        hbuf[(size_t)(grow >> 6) * 131072 + ((size_t)(c >> 3) * 64 + (grow & 63)) * 8 + (c & 7)] = f2bf(hval);
      }
  }
}

// ---------------- GEMM2: out[perm] = h @ w_out + b_out ----------------
// BM=128, BN=64, BK=64, 256 thr, 4 waves, wave 64m x 32n.
// A via 4x gload16 from hbuf panels; w_out via 4x dwordx4 + transpose + b64.
__global__ __launch_bounds__(256, 3) void gemm2n(
    const unsigned short* __restrict__ hbuf,
    const float* __restrict__ wo_, const float* __restrict__ bo_,
    const int* __restrict__ meta, const int* __restrict__ perm,
    float* __restrict__ out)
{
  const int bid = blockIdx.x;
  const int stripe = bid & 63;         // e*8+jn: same stripe -> same XCD (64%8==0)
  const int mt = bid >> 6;
  const int e = stripe >> 3, jn = stripe & 7;
  const int cnt = meta[e];
  const int m0 = mt * 128;
  if (m0 >= cnt) return;
  const int off = meta[NEXP + e], poff = meta[3 * NEXP + e];
  const int n0 = jn * 64;

  // per buf (24576 B): A[8 kq][128 m][8] @0 (16K) | B[8 oct][64 n][8] @16384 (8K)
  __shared__ __align__(16) unsigned char lds[49152];

  const int t = threadIdx.x;
  const int l = t & 63, w = t >> 6;
  const int wm = w >> 1, wn = w & 1;
  const int fr = l & 15, fg = l >> 4;

  const int tile0 = (poff + m0) >> 6;
  const float* wo = wo_ + (size_t)e * HID * DIM + n0;

  // B staging: ko = t&15 (k = ko*4+q), nq = t>>4 (n = nq*4)
  const int ko = t & 15, nq = t >> 4;
  const int bcol = nq * 4;
  const int boct = ko >> 1, bhalf = ko & 1;

  v4f acc[4][2];
  #pragma unroll
  for (int i = 0; i < 4; ++i) {
    acc[i][0] = (v4f){0.f, 0.f, 0.f, 0.f};
    acc[i][1] = (v4f){0.f, 0.f, 0.f, 0.f};
  }

  float4 ld0, ld1, ld2, ld3;
  auto bload = [&](int s) {
    const float* b = wo + (size_t)(s * 64 + ko * 4) * DIM + bcol;
    ld0 = *(const float4*)(b);
    ld1 = *(const float4*)(b + DIM);
    ld2 = *(const float4*)(b + 2 * DIM);
    ld3 = *(const float4*)(b + 3 * DIM);
  };
  auto bstore = [&](int b) {
    unsigned char* base = lds + b * 24576 + 16384;
    const float* f0 = (const float*)&ld0;
    const float* f1 = (const float*)&ld1;
    const float* f2 = (const float*)&ld2;
    const float* f3 = (const float*)&ld3;
    #pragma unroll
    for (int i = 0; i < 4; ++i) {
      ushort4 v;
      v.x = f2bf(f0[i]); v.y = f2bf(f1[i]);
      v.z = f2bf(f2[i]); v.w = f2bf(f3[i]);
      *(ushort4*)(base + (boct * 64 + bcol + i) * 16 + bhalf * 8) = v;
    }
  };
  auto aload = [&](int s, int b) {     // 4 gload16: chunks c = t + 256*i
    #pragma unroll
    for (int i = 0; i < 4; ++i) {
      const int c = t + 256 * i;
      const int kq = c >> 7, m = c & 127;
      gload16(hbuf + (size_t)(tile0 + (m >> 6)) * 131072 + ((size_t)(s * 8 + kq) * 64 + (m & 63)) * 8,
              lds + b * 24576 + c * 16);
    }
  };

  // prologue
  bload(0);
  bstore(0);
  aload(0, 0);
  __builtin_amdgcn_sched_barrier(0);   // REQUIRED: pin bload(1) BELOW aload(0) so
                                       // vmcnt(4) retires the gload16s, not the bloads
  bload(1);
  asm volatile("s_waitcnt vmcnt(4) lgkmcnt(0)" ::: "memory");  // retire aload(0)
  __builtin_amdgcn_sched_barrier(0);
  __builtin_amdgcn_s_barrier();
  __builtin_amdgcn_sched_barrier(0);

  int cur = 0;
  for (int s = 0; s < 32; ++s) {       // K = 2048 in 64-wide steps
    if (s < 31) aload(s + 1, cur ^ 1);
    const unsigned char* base = lds + cur * 24576;
    #pragma unroll
    for (int kk = 0; kk < 2; ++kk) {
      v8s af[4], bf[2];
      #pragma unroll
      for (int mf = 0; mf < 4; ++mf)
        af[mf] = *(const v8s*)(base + ((kk * 4 + fg) * 128 + wm * 64 + mf * 16 + fr) * 16);
      #pragma unroll
      for (int nf = 0; nf < 2; ++nf)
        bf[nf] = *(const v8s*)(base + 16384 + ((kk * 4 + fg) * 64 + wn * 32 + nf * 16 + fr) * 16);
      #pragma unroll
      for (int mf = 0; mf < 4; ++mf)
        #pragma unroll
        for (int nf = 0; nf < 2; ++nf)
          acc[mf][nf] = __builtin_amdgcn_mfma_f32_16x16x32_bf16(af[mf], bf[nf], acc[mf][nf], 0, 0, 0);
    }
    if (s < 31) {
      __builtin_amdgcn_sched_barrier(0);
      bstore(cur ^ 1);                 // implicit vmcnt(4)
      if (s < 30) {
        bload(s + 2);
        asm volatile("s_waitcnt vmcnt(4) lgkmcnt(0)" ::: "memory");
      } else {
        asm volatile("s_waitcnt vmcnt(0) lgkmcnt(0)" ::: "memory");
      }
      __builtin_amdgcn_sched_barrier(0);
      __builtin_amdgcn_s_barrier();
      __builtin_amdgcn_sched_barrier(0);
    }
    cur ^= 1;
  }

  #pragma unroll
  for (int nf = 0; nf < 2; ++nf) {
    const int c = n0 + wn * 32 + nf * 16 + fr;
    const float bo = bo_[(size_t)e * DIM + c];
    #pragma unroll
    for (int mf = 0; mf < 4; ++mf)
      #pragma unroll
      for (int jj = 0; jj < 4; ++jj) {
        const int r = wm * 64 + mf * 16 + fg * 4 + jj;
        if (m0 + r < cnt)
          out[(size_t)perm[off + m0 + r] * DIM + c] = acc[mf][nf][jj] + bo;
      }
  }
}

// ---------------- launch ----------------
extern "C" void kernel_launch(void* const* d_in, const int* in_sizes, int n_in,
                              void* d_out, int out_size, void* d_ws, size_t ws_size,
                              hipStream_t stream) {
  const float* x      = (const float*)d_in[0];
  const int*   route  = (const int*)d_in[1];
  const float* w_in   = (const float*)d_in[2];
  const float* b_in   = (const float*)d_in[3];
  const float* w_gate = (const float*)d_in[4];
  const float* b_gate = (const float*)d_in[5];
  const float* w_out  = (const float*)d_in[6];
  const float* b_out  = (const float*)d_in[7];
  float* out = (float*)d_out;

  const int ntok = in_sizes[1];  // 4096

  int* meta = (int*)d_ws;
  int* perm = (int*)((char*)d_ws + 128);

  // ws: meta/perm | xp 5.25MB | hbuf 21MB  (~26 MB total)
  unsigned short* xp   = (unsigned short*)((char*)d_ws + 65536);
  unsigned short* hbuf = (unsigned short*)((char*)d_ws + 65536 + 5242880);

  const int MT64  = (ntok + 63) / 64;
  const int MT128 = (ntok + 127) / 128;

  route_prep<<<1, 256, 0, stream>>>(route, meta, ntok);
  fill_perm<<<(ntok + 255) / 256, 256, 0, stream>>>(route, meta, perm, ntok);
  x_conv<<<NEXP * MT64, 256, 0, stream>>>(x, meta, perm, xp);
  gemm1n<<<256 * MT128, 256, 0, stream>>>(
      xp, w_gate, b_gate, w_in, b_in, meta, hbuf);
  gemm2n<<<64 * MT128, 256, 0, stream>>>(
      hbuf, w_out, b_out, meta, perm, out);
}

// Round 10
// 119.484 us; speedup vs baseline: 1.1775x; 1.1775x over previous
//
#include <hip/hip_runtime.h>

#define DIM 512
#define HID 2048
#define NEXP 8

typedef __attribute__((ext_vector_type(8))) short v8s;   // 8 x bf16 bits
typedef __attribute__((ext_vector_type(4))) float v4f;   // MFMA accumulator

__device__ __forceinline__ unsigned short f2bf(float f) {
  union { __bf16 b; unsigned short u; } c;
  c.b = (__bf16)f;
  return c.u;
}

__device__ __forceinline__ void gload16(const void* g, void* l) {
  __builtin_amdgcn_global_load_lds(
      (const __attribute__((address_space(1))) unsigned int*)g,
      (__attribute__((address_space(3))) unsigned int*)l, 16, 0, 0);
}

// ---------------- routing prep ----------------
__global__ void route_prep(const int* __restrict__ route, int* __restrict__ meta, int ntok) {
  __shared__ int c[NEXP];
  int t = threadIdx.x;
  if (t < NEXP) c[t] = 0;
  __syncthreads();
  for (int n = t; n < ntok; n += blockDim.x) atomicAdd(&c[route[n]], 1);
  __syncthreads();
  if (t == 0) {
    int acc = 0, pacc = 0;
    for (int e = 0; e < NEXP; ++e) {
      meta[e] = c[e];            // count
      meta[NEXP + e] = acc;      // exact offset
      meta[2 * NEXP + e] = acc;  // cursor for fill_perm
      meta[3 * NEXP + e] = pacc; // 128-padded offset (panel rows)
      acc += c[e];
      pacc += ((c[e] + 127) >> 7) << 7;
    }
  }
}

__global__ void fill_perm(const int* __restrict__ route, int* __restrict__ meta,
                          int* __restrict__ perm, int ntok) {
  int n = blockIdx.x * blockDim.x + threadIdx.x;
  if (n < ntok) {
    int p = atomicAdd(&meta[2 * NEXP + route[n]], 1);
    perm[p] = n;
  }
}

// ---------------- x conversion: gathered bf16 A-panels ----------------
// xp per 64-row tile: [kq 0..63][row 0..63][8k] bf16 = 32768 ushorts.
// Writes ALL 128-padded tiles (dup-clamped rows) so GEMM reads are deterministic.
__global__ __launch_bounds__(256) void x_conv(
    const float* __restrict__ x, const int* __restrict__ meta,
    const int* __restrict__ perm, unsigned short* __restrict__ xp)
{
  const int bid = blockIdx.x;
  const int e = bid & 7;
  const int mt = bid >> 3;
  const int cnt = meta[e];
  const int padded = ((cnt + 127) >> 7) << 7;
  if (mt * 64 >= padded) return;
  const int off  = meta[NEXP + e];
  const int poff = meta[3 * NEXP + e];
  const int t = threadIdx.x;
  const int r = t & 63, q = t >> 6;          // row, quarter (128 floats)
  int arow = mt * 64 + r; if (arow >= cnt) arow = cnt - 1;  // clamp (dup rows)
  const float* src = x + (size_t)perm[off + arow] * DIM + q * 128;
  unsigned short* dst = xp + (size_t)((poff + mt * 64) >> 6) * 32768;
  #pragma unroll
  for (int j = 0; j < 16; ++j) {
    float4 f0 = ((const float4*)src)[2 * j];
    float4 f1 = ((const float4*)src)[2 * j + 1];
    v8s v;
    v[0] = (short)f2bf(f0.x); v[1] = (short)f2bf(f0.y);
    v[2] = (short)f2bf(f0.z); v[3] = (short)f2bf(f0.w);
    v[4] = (short)f2bf(f1.x); v[5] = (short)f2bf(f1.y);
    v[6] = (short)f2bf(f1.z); v[7] = (short)f2bf(f1.w);
    *(v8s*)(dst + (size_t)((q * 16 + j) * 64 + r) * 8) = v;
  }
}

// ---------------- weight conversion to bf16 panels (r4-proven) ----------------
// wg/wi: per (e, j128-stripe): element (n,k) at ushort (s64*8192 + (kq*128+n)*8 + (k&7)).
__global__ __launch_bounds__(256) void wgi_conv(
    const float* __restrict__ wg, const float* __restrict__ wi,
    unsigned short* __restrict__ wgp, unsigned short* __restrict__ wip)
{
  const int s = blockIdx.x;            // 64-K chunk (8)
  const int j = blockIdx.y;            // n-stripe of 128 (16)
  const int e = blockIdx.z >> 1;
  const int which = blockIdx.z & 1;
  const float* src = (which ? wi : wg) + (size_t)e * DIM * HID;
  unsigned short* dst = (which ? wip : wgp) + (((size_t)e * 16 + j) * 8 + s) * 8192;
  const int t = threadIdx.x;
  #pragma unroll
  for (int i = 0; i < 4; ++i) {
    const int c = t + 256 * i;         // chunk in [0,1024)
    const int kq = c >> 7, n = c & 127;
    const float* srow = src + (size_t)(s * 64 + kq * 8) * HID + j * 128 + n;
    v8s r;
    #pragma unroll
    for (int q = 0; q < 8; ++q) r[q] = (short)f2bf(srow[(size_t)q * HID]);
    *(v8s*)(dst + (size_t)c * 8) = r;
  }
}

// w_out: per (e, j64-stripe): [s64(32)][kq(8)][n(64)][8k].
__global__ __launch_bounds__(256) void wo_conv(
    const float* __restrict__ wo, unsigned short* __restrict__ wop)
{
  const int s = blockIdx.x;            // 64-K chunk (32)
  const int j = blockIdx.y;            // n-stripe of 64 (8)
  const int e = blockIdx.z;
  const float* src = wo + (size_t)e * HID * DIM;
  unsigned short* dst = wop + (((size_t)e * 8 + j) * 32 + s) * 4096;
  const int t = threadIdx.x;
  #pragma unroll
  for (int i = 0; i < 2; ++i) {
    const int c = t + 256 * i;         // chunk in [0,512)
    const int kq = c >> 6, n = c & 63;
    const float* srow = src + (size_t)(s * 64 + kq * 8) * DIM + j * 64 + n;
    v8s r;
    #pragma unroll
    for (int q = 0; q < 8; ++q) r[q] = (short)f2bf(srow[(size_t)q * DIM]);
    *(v8s*)(dst + (size_t)c * 8) = r;
  }
}

// ---------------- GEMM1: h = silu(x@wg+bg)*(x@wi+bi) -> hbuf panels ----------------
// BM=128, BN=64(G)+64(I), BK=32, 256 thr, 4 waves 2x2, wave 64m x 32n on BOTH.
// ALL staging via gload16 (4/thread/step): A 2, G 1, I 1. 8 ds_read_b128 per
// 16 MFMA (ratio 0.5). dbuf 2x16KB, 4 blk/CU, ~1100 active blocks.
__global__ __launch_bounds__(256, 4) void gemm1g(
    const unsigned short* __restrict__ xp,
    const unsigned short* __restrict__ wgp, const float* __restrict__ bg_,
    const unsigned short* __restrict__ wip, const float* __restrict__ bi_,
    const int* __restrict__ meta,
    unsigned short* __restrict__ hbuf)
{
  const int bid = blockIdx.x;
  const int stripe = bid & 255;        // e*32 + j: stripe fixed -> same XCD across mt
  const int mt = bid >> 8;
  const int e = stripe >> 5, j = stripe & 31;   // j: 64-col stripe
  const int cnt = meta[e];
  const int m0 = mt * 128;
  if (m0 >= cnt) return;
  const int poff = meta[3 * NEXP + e];
  const int n0 = j * 64;

  // per buf (16384 B): A[4 kq][128 m][8] @0 (8K) | G[4 kq][64 n][8] @8192 | I @12288
  __shared__ __align__(16) unsigned char lds[32768];

  const int t = threadIdx.x;
  const int l = t & 63, w = t >> 6;
  const int wm = w >> 1, wn = w & 1;
  const int fr = l & 15, fg = l >> 4;

  const int tile0 = (poff + m0) >> 6;
  const int half = j & 1;
  const unsigned short* pg = wgp + ((size_t)e * 16 + (j >> 1)) * 65536;
  const unsigned short* pi = wip + ((size_t)e * 16 + (j >> 1)) * 65536;

  // staging indices
  const int aq0 = t >> 7, am0 = t & 127;         // A chunk i=0
  const int aq1 = (t + 256) >> 7, am1 = t & 127; // A chunk i=1 (aq1 = aq0+2)
  const int gq = t >> 6, gn = t & 63;            // G/I chunk

  v4f aG[4][2], aI[4][2];
  #pragma unroll
  for (int i = 0; i < 4; ++i)
    #pragma unroll
    for (int q = 0; q < 2; ++q) {
      aG[i][q] = (v4f){0.f, 0.f, 0.f, 0.f};
      aI[i][q] = (v4f){0.f, 0.f, 0.f, 0.f};
    }

  auto stage = [&](int s, int b) {
    unsigned char* base = lds + b * 16384;
    // A: [kq = s*4 + q][m][8]
    gload16(xp + (size_t)(tile0 + (am0 >> 6)) * 32768 + ((size_t)(s * 4 + aq0) * 64 + (am0 & 63)) * 8,
            base + t * 16);
    gload16(xp + (size_t)(tile0 + (am1 >> 6)) * 32768 + ((size_t)(s * 4 + aq1) * 64 + (am1 & 63)) * 8,
            base + (t + 256) * 16);
    // G/I: panel (e, j>>1): s64 = s>>1, kq = (s&1)*4 + gq, n128 = half*64 + gn
    const size_t woff = (size_t)(s >> 1) * 8192 + ((size_t)((s & 1) * 4 + gq) * 128 + half * 64 + gn) * 8;
    gload16(pg + woff, base + 8192 + t * 16);
    gload16(pi + woff, base + 12288 + t * 16);
  };

  stage(0, 0);
  __syncthreads();

  int cur = 0;
  for (int s = 0; s < 16; ++s) {       // K = 512 in 32-wide steps
    if (s < 15) stage(s + 1, cur ^ 1); // prefetch before compute
    const unsigned char* base = lds + cur * 16384;
    v8s af[4], gf[2], inf[2];
    #pragma unroll
    for (int mf = 0; mf < 4; ++mf)
      af[mf] = *(const v8s*)(base + (fg * 128 + wm * 64 + mf * 16 + fr) * 16);
    #pragma unroll
    for (int nf = 0; nf < 2; ++nf) {
      gf[nf]  = *(const v8s*)(base + 8192  + (fg * 64 + wn * 32 + nf * 16 + fr) * 16);
      inf[nf] = *(const v8s*)(base + 12288 + (fg * 64 + wn * 32 + nf * 16 + fr) * 16);
    }
    #pragma unroll
    for (int mf = 0; mf < 4; ++mf)
      #pragma unroll
      for (int nf = 0; nf < 2; ++nf) {
        aG[mf][nf] = __builtin_amdgcn_mfma_f32_16x16x32_bf16(af[mf], gf[nf],  aG[mf][nf], 0, 0, 0);
        aI[mf][nf] = __builtin_amdgcn_mfma_f32_16x16x32_bf16(af[mf], inf[nf], aI[mf][nf], 0, 0, 0);
      }
    __syncthreads();
    cur ^= 1;
  }

  // epilogue: bias + SiLU(gate)*in -> hbuf panels (pad rows deterministic)
  #pragma unroll
  for (int nf = 0; nf < 2; ++nf) {
    const int c = n0 + wn * 32 + nf * 16 + fr;        // k-dim of gemm2
    const float bg = bg_[(size_t)e * HID + c];
    const float bi = bi_[(size_t)e * HID + c];
    #pragma unroll
    for (int mf = 0; mf < 4; ++mf)
      #pragma unroll
      for (int jj = 0; jj < 4; ++jj) {
        const int r = wm * 64 + mf * 16 + fg * 4 + jj;  // 0..127
        const float g = aG[mf][nf][jj] + bg;
        const float v = aI[mf][nf][jj] + bi;
        const float hval = g / (1.f + __expf(-g)) * v;
        const int grow = poff + m0 + r;
        hbuf[(size_t)(grow >> 6) * 131072 + ((size_t)(c >> 3) * 64 + (grow & 63)) * 8 + (c & 7)] = f2bf(hval);
      }
  }
}

// ---------------- GEMM2: out[perm] = h @ w_out + b_out ----------------
// BM=64, BN=64, BK=64, 256 thr, 4 waves 2x2, wave 32x32.
// Both operands via gload16 (4/thread/step). dbuf 2x16KB, ~528 active blocks.
__global__ __launch_bounds__(256, 4) void gemm2g(
    const unsigned short* __restrict__ hbuf,
    const unsigned short* __restrict__ wop, const float* __restrict__ bo_,
    const int* __restrict__ meta, const int* __restrict__ perm,
    float* __restrict__ out)
{
  const int bid = blockIdx.x;
  const int stripe = bid & 63;         // e*8 + jn
  const int mt = bid >> 6;
  const int e = stripe >> 3, jn = stripe & 7;
  const int cnt = meta[e];
  const int m0 = mt * 64;
  if (m0 >= cnt) return;
  const int off = meta[NEXP + e], poff = meta[3 * NEXP + e];
  const int n0 = jn * 64;

  // per buf (16384 B): A[8 kq][64 m][8] @0 (8K) | B[8 kq][64 n][8] @8192 (8K)
  __shared__ __align__(16) unsigned char lds[32768];

  const int t = threadIdx.x;
  const int l = t & 63, w = t >> 6;
  const int wm = w >> 1, wn = w & 1;
  const int fr = l & 15, fg = l >> 4;

  const unsigned short* pa = hbuf + (size_t)((poff + m0) >> 6) * 131072;
  const unsigned short* pb = wop + ((size_t)e * 8 + jn) * 131072;

  v4f acc[2][2];
  #pragma unroll
  for (int i = 0; i < 2; ++i) {
    acc[i][0] = (v4f){0.f, 0.f, 0.f, 0.f};
    acc[i][1] = (v4f){0.f, 0.f, 0.f, 0.f};
  }

  auto stage = [&](int s, int b) {
    unsigned char* base = lds + b * 16384;
    #pragma unroll
    for (int i = 0; i < 2; ++i) {      // A: 8 KB
      const int c = t + 256 * i;
      gload16(pa + (size_t)s * 4096 + (size_t)c * 8, base + c * 16);
    }
    #pragma unroll
    for (int i = 0; i < 2; ++i) {      // B: 8 KB
      const int c = t + 256 * i;
      gload16(pb + (size_t)s * 4096 + (size_t)c * 8, base + 8192 + c * 16);
    }
  };

  stage(0, 0);
  __syncthreads();

  int cur = 0;
  for (int s = 0; s < 32; ++s) {       // K = 2048 in 64-wide steps
    if (s < 31) stage(s + 1, cur ^ 1);
    const unsigned char* base = lds + cur * 16384;
    #pragma unroll
    for (int kk = 0; kk < 2; ++kk) {
      v8s af[2], bf[2];
      #pragma unroll
      for (int mf = 0; mf < 2; ++mf)
        af[mf] = *(const v8s*)(base + ((kk * 4 + fg) * 64 + wm * 32 + mf * 16 + fr) * 16);
      #pragma unroll
      for (int nf = 0; nf < 2; ++nf)
        bf[nf] = *(const v8s*)(base + 8192 + ((kk * 4 + fg) * 64 + wn * 32 + nf * 16 + fr) * 16);
      #pragma unroll
      for (int mf = 0; mf < 2; ++mf)
        #pragma unroll
        for (int nf = 0; nf < 2; ++nf)
          acc[mf][nf] = __builtin_amdgcn_mfma_f32_16x16x32_bf16(af[mf], bf[nf], acc[mf][nf], 0, 0, 0);
    }
    __syncthreads();
    cur ^= 1;
  }

  #pragma unroll
  for (int nf = 0; nf < 2; ++nf) {
    const int c = n0 + wn * 32 + nf * 16 + fr;
    const float bo = bo_[(size_t)e * DIM + c];
    #pragma unroll
    for (int mf = 0; mf < 2; ++mf)
      #pragma unroll
      for (int jj = 0; jj < 4; ++jj) {
        const int r = wm * 32 + mf * 16 + fg * 4 + jj;
        if (m0 + r < cnt)
          out[(size_t)perm[off + m0 + r] * DIM + c] = acc[mf][nf][jj] + bo;
      }
  }
}

// ---------------- launch ----------------
extern "C" void kernel_launch(void* const* d_in, const int* in_sizes, int n_in,
                              void* d_out, int out_size, void* d_ws, size_t ws_size,
                              hipStream_t stream) {
  const float* x      = (const float*)d_in[0];
  const int*   route  = (const int*)d_in[1];
  const float* w_in   = (const float*)d_in[2];
  const float* b_in   = (const float*)d_in[3];
  const float* w_gate = (const float*)d_in[4];
  const float* b_gate = (const float*)d_in[5];
  const float* w_out  = (const float*)d_in[6];
  const float* b_out  = (const float*)d_in[7];
  float* out = (float*)d_out;

  const int ntok = in_sizes[1];  // 4096

  int* meta = (int*)d_ws;
  int* perm = (int*)((char*)d_ws + 128);

  // ws: meta/perm 64K | W-region 32MB (wgp+wip; wop aliases wgp after gemm1)
  //   | xp 5.25MB | hbuf 20MB   -> ~58 MB total
  const size_t W_OFF  = 65536;
  const size_t WMAT   = (size_t)NEXP * DIM * HID * 2;   // 16 MiB
  unsigned short* wgp  = (unsigned short*)((char*)d_ws + W_OFF);
  unsigned short* wip  = (unsigned short*)((char*)d_ws + W_OFF + WMAT);
  unsigned short* wop  = wgp;  // reused AFTER gemm1g consumed wgp
  unsigned short* xp   = (unsigned short*)((char*)d_ws + W_OFF + 2 * WMAT);
  unsigned short* hbuf = (unsigned short*)((char*)d_ws + W_OFF + 2 * WMAT + 5242880);

  const int MT64  = (ntok + 63) / 64;
  const int MT128 = (ntok + 127) / 128;

  route_prep<<<1, 256, 0, stream>>>(route, meta, ntok);
  fill_perm<<<(ntok + 255) / 256, 256, 0, stream>>>(route, meta, perm, ntok);
  x_conv<<<NEXP * MT64, 256, 0, stream>>>(x, meta, perm, xp);
  wgi_conv<<<dim3(8, 16, 16), 256, 0, stream>>>(w_gate, w_in, wgp, wip);
  gemm1g<<<256 * MT128, 256, 0, stream>>>(
      xp, wgp, b_gate, wip, b_in, meta, hbuf);
  wo_conv<<<dim3(32, 8, 8), 256, 0, stream>>>(w_out, wop);
  gemm2g<<<64 * MT64, 256, 0, stream>>>(
      hbuf, wop, b_out, meta, perm, out);
}